// Round 3
// baseline (261.274 us; speedup 1.0000x reference)
//
#include <hip/hip_runtime.h>

// RandomSelfAttention: B=2, S=4096, S2=2048, NH=8, H=64, NKEYS=64
// q:(B,S2,NH,H) f32, k/v:(B,S,NH,H) f32, idx:(B,S2,NKEYS) int
// out z:(B,S2,NH,H) f32
//
// One wave per (b,q,n). Lane = (g=lane>>4, hc=lane&15).
// Phase1: per iter, 4 k-rows (keys it*4+g) read coalesced 16 lanes/row
// (float4 each) -> 16 lines/instr instead of 64; dot finished by 4-step
// shfl_xor butterfly within the 16-lane group. Phase2: same layout for v,
// float4 loads, per-group z accumulate + 2-step cross-group reduce.
// No LDS, no barriers; offsets broadcast via __shfl.
// Block swizzle: blockIdx%16 = (b,n) combo -> per-XCD L2 working set ~4MB.

#define BB 2
#define SS 4096
#define S2V 2048
#define NHV 8
#define HV 64
#define NKV 64

__global__ __launch_bounds__(256, 8)
void rsa_kernel(const float* __restrict__ q, const float* __restrict__ k,
                const float* __restrict__ v, const int* __restrict__ idx,
                float* __restrict__ out) {
    const int lane = threadIdx.x & 63;
    const int w    = threadIdx.x >> 6;
    const int bi   = blockIdx.x;

    const int combo = bi & 15;
    const int b     = combo >> 3;
    const int n     = combo & 7;
    const int qi    = ((bi >> 4) << 2) + w;

    const int g  = lane >> 4;    // key group 0..3
    const int hc = lane & 15;    // h-chunk 0..15 (float4 granularity)

    const size_t bq = (size_t)b * S2V + qi;

    // q chunk for this lane (prescaled by h^-0.5 = 1/8), broadcast across groups
    const float* qrow = q + (bq * NHV + n) * HV;
    const float4 qv = *(const float4*)(qrow + hc * 4);
    const float4 q4 = make_float4(qv.x * 0.125f, qv.y * 0.125f,
                                  qv.z * 0.125f, qv.w * 0.125f);

    // my key's row element-offset; broadcast all 64 into per-lane table of 16
    const int my_off = idx[bq * NKV + lane] * (NHV * HV);

    int offs[16];
#pragma unroll
    for (int it = 0; it < 16; ++it)
        offs[it] = __shfl(my_off, it * 4 + g, 64);

    const float* kb = k + ((size_t)b * SS * NHV + n) * HV;
    const float* vb = v + ((size_t)b * SS * NHV + n) * HV;

    // ---- phase 1: scores. iter it covers keys it*4 + g ----
    float sc[16];
#pragma unroll
    for (int it = 0; it < 16; ++it) {
        const float4 k4 = *(const float4*)(kb + offs[it] + hc * 4);
        float d = k4.x * q4.x + k4.y * q4.y + k4.z * q4.z + k4.w * q4.w;
        d += __shfl_xor(d, 1);
        d += __shfl_xor(d, 2);
        d += __shfl_xor(d, 4);
        d += __shfl_xor(d, 8);
        sc[it] = d;   // full dot of key it*4+g, replicated over 16-lane group
    }

    // ---- softmax over 64 keys ----
    float m = sc[0];
#pragma unroll
    for (int it = 1; it < 16; ++it) m = fmaxf(m, sc[it]);
    m = fmaxf(m, __shfl_xor(m, 16));
    m = fmaxf(m, __shfl_xor(m, 32));

    float ssum = 0.f;
#pragma unroll
    for (int it = 0; it < 16; ++it) {
        sc[it] = __expf(sc[it] - m);
        ssum += sc[it];
    }
    ssum += __shfl_xor(ssum, 16);
    ssum += __shfl_xor(ssum, 32);
    const float rs = __frcp_rn(ssum);

    // ---- phase 2: z = sum_key p[key] * v_row[key], same lane layout ----
    float4 z = make_float4(0.f, 0.f, 0.f, 0.f);
#pragma unroll
    for (int it = 0; it < 16; ++it) {
        const float4 v4 = *(const float4*)(vb + offs[it] + hc * 4);
        const float p = sc[it];
        z.x = fmaf(p, v4.x, z.x);
        z.y = fmaf(p, v4.y, z.y);
        z.z = fmaf(p, v4.z, z.z);
        z.w = fmaf(p, v4.w, z.w);
    }
    // reduce partial z across the 4 key groups
    z.x += __shfl_xor(z.x, 16); z.y += __shfl_xor(z.y, 16);
    z.z += __shfl_xor(z.z, 16); z.w += __shfl_xor(z.w, 16);
    z.x += __shfl_xor(z.x, 32); z.y += __shfl_xor(z.y, 32);
    z.z += __shfl_xor(z.z, 32); z.w += __shfl_xor(z.w, 32);

    if (g == 0) {
        float4 zo = make_float4(z.x * rs, z.y * rs, z.z * rs, z.w * rs);
        *(float4*)(out + (bq * NHV + n) * HV + hc * 4) = zo;
    }
}

extern "C" void kernel_launch(void* const* d_in, const int* in_sizes, int n_in,
                              void* d_out, int out_size, void* d_ws, size_t ws_size,
                              hipStream_t stream) {
    const float* q   = (const float*)d_in[0];
    const float* k   = (const float*)d_in[1];
    const float* v   = (const float*)d_in[2];
    const int*   idx = (const int*)d_in[3];
    float*       out = (float*)d_out;

    const int n_units = BB * S2V * NHV;       // 32768 waves
    const int blocks  = n_units / 4;          // 8192 blocks of 4 waves
    rsa_kernel<<<blocks, 256, 0, stream>>>(q, k, v, idx, out);
}

// Round 4
// 125.404 us; speedup vs baseline: 2.0835x; 2.0835x over previous
//
#include <hip/hip_runtime.h>

// RandomSelfAttention: B=2, S=4096, S2=2048, NH=8, H=64, NKEYS=64
// q:(B,S2,NH,H) f32, k/v:(B,S,NH,H) f32, idx:(B,S2,NKEYS) int
// out z:(B,S2,NH,H) f32
//
// One wave per (b,q,n). Lane = (g=lane>>4, hc=lane&15).
// Phase1: per iter, 4 k-rows (keys it*4+g) read coalesced 16 lanes/row
// (float4 each) -> 16 lines/instr instead of 64; dot finished by 4-step
// shfl_xor butterfly within the 16-lane group. Phase2: same layout for v,
// float4 loads, per-group z accumulate + 2-step cross-group reduce.
// No LDS, no barriers; offsets broadcast via __shfl.
// Block swizzle: blockIdx%16 = (b,n) combo -> per-XCD L2 working set ~4MB.
//
// __launch_bounds__(256,4): 128-VGPR budget. (256,8) capped at 64 VGPRs and
// spilled offs[16]+sc[16] to scratch -> 750MB HBM scratch traffic, 195us
// (round 3 post-mortem). Do not tighten without checking VGPR_Count.

#define BB 2
#define SS 4096
#define S2V 2048
#define NHV 8
#define HV 64
#define NKV 64

__global__ __launch_bounds__(256, 4)
void rsa_kernel(const float* __restrict__ q, const float* __restrict__ k,
                const float* __restrict__ v, const int* __restrict__ idx,
                float* __restrict__ out) {
    const int lane = threadIdx.x & 63;
    const int w    = threadIdx.x >> 6;
    const int bi   = blockIdx.x;

    const int combo = bi & 15;
    const int b     = combo >> 3;
    const int n     = combo & 7;
    const int qi    = ((bi >> 4) << 2) + w;

    const int g  = lane >> 4;    // key group 0..3
    const int hc = lane & 15;    // h-chunk 0..15 (float4 granularity)

    const size_t bq = (size_t)b * S2V + qi;

    // q chunk for this lane (prescaled by h^-0.5 = 1/8), broadcast across groups
    const float* qrow = q + (bq * NHV + n) * HV;
    const float4 qv = *(const float4*)(qrow + hc * 4);
    const float4 q4 = make_float4(qv.x * 0.125f, qv.y * 0.125f,
                                  qv.z * 0.125f, qv.w * 0.125f);

    // my key's row element-offset; broadcast all 64 into per-lane table of 16
    const int my_off = idx[bq * NKV + lane] * (NHV * HV);

    int offs[16];
#pragma unroll
    for (int it = 0; it < 16; ++it)
        offs[it] = __shfl(my_off, it * 4 + g, 64);

    const float* kb = k + ((size_t)b * SS * NHV + n) * HV;
    const float* vb = v + ((size_t)b * SS * NHV + n) * HV;

    // ---- phase 1: scores. iter it covers keys it*4 + g ----
    float sc[16];
#pragma unroll
    for (int it = 0; it < 16; ++it) {
        const float4 k4 = *(const float4*)(kb + offs[it] + hc * 4);
        float d = k4.x * q4.x + k4.y * q4.y + k4.z * q4.z + k4.w * q4.w;
        d += __shfl_xor(d, 1);
        d += __shfl_xor(d, 2);
        d += __shfl_xor(d, 4);
        d += __shfl_xor(d, 8);
        sc[it] = d;   // full dot of key it*4+g, replicated over 16-lane group
    }

    // ---- softmax over 64 keys ----
    float m = sc[0];
#pragma unroll
    for (int it = 1; it < 16; ++it) m = fmaxf(m, sc[it]);
    m = fmaxf(m, __shfl_xor(m, 16));
    m = fmaxf(m, __shfl_xor(m, 32));

    float ssum = 0.f;
#pragma unroll
    for (int it = 0; it < 16; ++it) {
        sc[it] = __expf(sc[it] - m);
        ssum += sc[it];
    }
    ssum += __shfl_xor(ssum, 16);
    ssum += __shfl_xor(ssum, 32);
    const float rs = __frcp_rn(ssum);

    // ---- phase 2: z = sum_key p[key] * v_row[key], same lane layout ----
    float4 z = make_float4(0.f, 0.f, 0.f, 0.f);
#pragma unroll
    for (int it = 0; it < 16; ++it) {
        const float4 v4 = *(const float4*)(vb + offs[it] + hc * 4);
        const float p = sc[it];
        z.x = fmaf(p, v4.x, z.x);
        z.y = fmaf(p, v4.y, z.y);
        z.z = fmaf(p, v4.z, z.z);
        z.w = fmaf(p, v4.w, z.w);
    }
    // reduce partial z across the 4 key groups
    z.x += __shfl_xor(z.x, 16); z.y += __shfl_xor(z.y, 16);
    z.z += __shfl_xor(z.z, 16); z.w += __shfl_xor(z.w, 16);
    z.x += __shfl_xor(z.x, 32); z.y += __shfl_xor(z.y, 32);
    z.z += __shfl_xor(z.z, 32); z.w += __shfl_xor(z.w, 32);

    if (g == 0) {
        float4 zo = make_float4(z.x * rs, z.y * rs, z.z * rs, z.w * rs);
        *(float4*)(out + (bq * NHV + n) * HV + hc * 4) = zo;
    }
}

extern "C" void kernel_launch(void* const* d_in, const int* in_sizes, int n_in,
                              void* d_out, int out_size, void* d_ws, size_t ws_size,
                              hipStream_t stream) {
    const float* q   = (const float*)d_in[0];
    const float* k   = (const float*)d_in[1];
    const float* v   = (const float*)d_in[2];
    const int*   idx = (const int*)d_in[3];
    float*       out = (float*)d_out;

    const int n_units = BB * S2V * NHV;       // 32768 waves
    const int blocks  = n_units / 4;          // 8192 blocks of 4 waves
    rsa_kernel<<<blocks, 256, 0, stream>>>(q, k, v, idx, out);
}

// Round 5
// 123.658 us; speedup vs baseline: 2.1129x; 1.0141x over previous
//
#include <hip/hip_runtime.h>

// RandomSelfAttention: B=2, S=4096, S2=2048, NH=8, H=64, NKEYS=64
// q:(B,S2,NH,H) f32, k/v:(B,S,NH,H) f32, idx:(B,S2,NKEYS) int
// out z:(B,S2,NH,H) f32
//
// One wave per (b,q,n). Lane = (g=lane>>4, hc=lane&15).
// Phase1: per iter, 4 k-rows AND 4 v-rows (keys it*4+g) read coalesced
// 16 lanes/row (float4 each); v rows held in vr[16] registers so phase 2
// has NO memory wall (v is independent of softmax — compiler wouldn't
// hoist it on its own, VGPR count proved that in round 4).
// Dot finished by 4-step shfl_xor butterfly in the 16-lane group.
// offs shuffle sunk into the loop to keep VGPRs under the (256,4)=128 budget.
// Block swizzle: blockIdx%16 = (b,n) combo -> per-XCD L2 working set ~4MB.
//
// __launch_bounds__(256,4): 128-VGPR budget. (256,8) spilled catastrophically
// (round 3: 750MB scratch traffic). Watch WRITE_SIZE for spills on any edit.

#define BB 2
#define SS 4096
#define S2V 2048
#define NHV 8
#define HV 64
#define NKV 64

__global__ __launch_bounds__(256, 4)
void rsa_kernel(const float* __restrict__ q, const float* __restrict__ k,
                const float* __restrict__ v, const int* __restrict__ idx,
                float* __restrict__ out) {
    const int lane = threadIdx.x & 63;
    const int w    = threadIdx.x >> 6;
    const int bi   = blockIdx.x;

    const int combo = bi & 15;
    const int b     = combo >> 3;
    const int n     = combo & 7;
    const int qi    = ((bi >> 4) << 2) + w;

    const int g  = lane >> 4;    // key group 0..3
    const int hc = lane & 15;    // h-chunk 0..15 (float4 granularity)

    const size_t bq = (size_t)b * S2V + qi;

    // q chunk for this lane (prescaled by h^-0.5 = 1/8)
    const float* qrow = q + (bq * NHV + n) * HV;
    const float4 qv = *(const float4*)(qrow + hc * 4);
    const float4 q4 = make_float4(qv.x * 0.125f, qv.y * 0.125f,
                                  qv.z * 0.125f, qv.w * 0.125f);

    const int my_off = idx[bq * NKV + lane] * (NHV * HV);

    const float* kb = k + ((size_t)b * SS * NHV + n) * HV;
    const float* vb = v + ((size_t)b * SS * NHV + n) * HV;

    // ---- phase 1: k dots + v prefetch. iter it covers keys it*4 + g ----
    float  sc[16];
    float4 vr[16];
#pragma unroll
    for (int it = 0; it < 16; ++it) {
        const int off = __shfl(my_off, it * 4 + g, 64);   // key (it*4+g)'s row
        const float4 k4 = *(const float4*)(kb + off + hc * 4);
        vr[it] = *(const float4*)(vb + off + hc * 4);
        float d = k4.x * q4.x + k4.y * q4.y + k4.z * q4.z + k4.w * q4.w;
        d += __shfl_xor(d, 1);
        d += __shfl_xor(d, 2);
        d += __shfl_xor(d, 4);
        d += __shfl_xor(d, 8);
        sc[it] = d;   // full dot of key it*4+g, replicated over 16-lane group
    }

    // ---- softmax over 64 keys (v loads still draining underneath) ----
    float m = sc[0];
#pragma unroll
    for (int it = 1; it < 16; ++it) m = fmaxf(m, sc[it]);
    m = fmaxf(m, __shfl_xor(m, 16));
    m = fmaxf(m, __shfl_xor(m, 32));

    float ssum = 0.f;
#pragma unroll
    for (int it = 0; it < 16; ++it) {
        sc[it] = __expf(sc[it] - m);
        ssum += sc[it];
    }
    ssum += __shfl_xor(ssum, 16);
    ssum += __shfl_xor(ssum, 32);
    const float rs = __frcp_rn(ssum);

    // ---- phase 2: pure VALU — z = sum_key p[key] * v_row[key] ----
    float4 z = make_float4(0.f, 0.f, 0.f, 0.f);
#pragma unroll
    for (int it = 0; it < 16; ++it) {
        const float p = sc[it];
        z.x = fmaf(p, vr[it].x, z.x);
        z.y = fmaf(p, vr[it].y, z.y);
        z.z = fmaf(p, vr[it].z, z.z);
        z.w = fmaf(p, vr[it].w, z.w);
    }
    // reduce partial z across the 4 key groups
    z.x += __shfl_xor(z.x, 16); z.y += __shfl_xor(z.y, 16);
    z.z += __shfl_xor(z.z, 16); z.w += __shfl_xor(z.w, 16);
    z.x += __shfl_xor(z.x, 32); z.y += __shfl_xor(z.y, 32);
    z.z += __shfl_xor(z.z, 32); z.w += __shfl_xor(z.w, 32);

    if (g == 0) {
        float4 zo = make_float4(z.x * rs, z.y * rs, z.z * rs, z.w * rs);
        *(float4*)(out + (bq * NHV + n) * HV + hc * 4) = zo;
    }
}

extern "C" void kernel_launch(void* const* d_in, const int* in_sizes, int n_in,
                              void* d_out, int out_size, void* d_ws, size_t ws_size,
                              hipStream_t stream) {
    const float* q   = (const float*)d_in[0];
    const float* k   = (const float*)d_in[1];
    const float* v   = (const float*)d_in[2];
    const int*   idx = (const int*)d_in[3];
    float*       out = (float*)d_out;

    const int n_units = BB * S2V * NHV;       // 32768 waves
    const int blocks  = n_units / 4;          // 8192 blocks of 4 waves
    rsa_kernel<<<blocks, 256, 0, stream>>>(q, k, v, idx, out);
}